// Round 5
// baseline (435.297 us; speedup 1.0000x reference)
//
#include <hip/hip_runtime.h>
#include <cstddef>
#include <cstdint>

#define BATCH 32
#define QL 4
#define DIM 2048
#define NH 16
#define HD 128
#define KVLEN 8192
#define HQ 64          // NH*QL
#define CHUNK 512
#define NCK 16         // KVLEN / CHUNK
#define KT 64          // kv rows per tile
#define NT 8           // CHUNK / KT

typedef __attribute__((ext_vector_type(8))) short bf16x8;   // 8 bf16 (4 VGPRs)
typedef __attribute__((ext_vector_type(4))) float f32x4;    // MFMA C/D

__device__ __forceinline__ unsigned short cvt_bf16(float f) {
    unsigned int u = __builtin_bit_cast(unsigned int, f);
    u += 0x7fffu + ((u >> 16) & 1u);            // RNE
    return (unsigned short)(u >> 16);
}
__device__ __forceinline__ unsigned int pack2(float a, float b) {
    return (unsigned int)cvt_bf16(a) | ((unsigned int)cvt_bf16(b) << 16);
}
__device__ __forceinline__ float bf16_to_f32(unsigned short s) {
    unsigned int u = ((unsigned int)s) << 16;
    return __builtin_bit_cast(float, u);
}
__device__ __forceinline__ bf16x8 mk_frag(unsigned int a, unsigned int b,
                                          unsigned int c, unsigned int d) {
    unsigned int t[4] = {a, b, c, d};
    return *(const bf16x8*)t;
}

// ---------------------------------------------------------------------------
// GEMM core: C[128,N] = A[128,K=2048] @ W, split-K x4 (blockIdx.z), each
// split does K=512 in 8 BK=64 iters; epilogue fp32 atomicAdd into zeroed
// output, bias added only by the z==0 split. (R3 verified: split-K 8 vs 4
// is perf-neutral -> atomics are not the hidden cost; keep 4.)
// grid (N/64, 2, 4), block 256 (4 waves). Register prefetch of next iter's
// A/W during MFMA of current.
// variant 0: N=2304 fused QKV -> qws/kws/vws scatter with bq/bk/bv.
// variant 1: N=2048 -> out with bo.
// ---------------------------------------------------------------------------
template<int VARIANT>
__global__ __launch_bounds__(256) void gemm_kernel(
    const float* __restrict__ A,
    const float* __restrict__ w0p, const float* __restrict__ w1p,
    const float* __restrict__ w2p,
    const float* __restrict__ b0p, const float* __restrict__ b1p,
    const float* __restrict__ b2p,
    float* __restrict__ o0, float* __restrict__ o1, float* __restrict__ o2)
{
    const int n0 = blockIdx.x * 64;
    const int m0 = blockIdx.y * 64;
    const int kz = blockIdx.z * 512;        // split-K base
    const int tid = threadIdx.x;
    const int wave = tid >> 6, lane = tid & 63;
    const int l15 = lane & 15, quad = lane >> 4;

    const float* W; const float* Bv; int ldw, nc;
    if (VARIANT == 0) {
        if (n0 >= 2176)      { W = w2p; Bv = b2p; ldw = 128;  nc = n0 - 2176; }
        else if (n0 >= 2048) { W = w1p; Bv = b1p; ldw = 128;  nc = n0 - 2048; }
        else                 { W = w0p; Bv = b0p; ldw = 2048; nc = n0; }
    } else { W = w0p; Bv = b0p; ldw = 2048; nc = n0; }

    __shared__ alignas(16) unsigned short a_s[64][72];   // [m][k], 144B rows
    __shared__ alignas(16) unsigned short w_s[64][68];   // [n][k], 136B rows

    // staging coords
    const int wn = tid & 63;            // W: n within tile
    const int wk0 = (tid >> 6) * 4;     // W: k quad base (+16*sub)

    f32x4 acc[4];
    #pragma unroll
    for (int nt = 0; nt < 4; ++nt) acc[nt] = (f32x4){0.f, 0.f, 0.f, 0.f};

    float4 apre[4];
    float wpre[4][4];                   // [sub][j]

    // initial prefetch (kb = kz)
    #pragma unroll
    for (int ii = 0; ii < 4; ++ii) {
        int f = tid + 256 * ii, r = f >> 4, c4 = (f & 15) << 2;
        apre[ii] = *(const float4*)&A[(size_t)(m0 + r) * DIM + kz + c4];
    }
    #pragma unroll
    for (int sub = 0; sub < 4; ++sub) {
        int k0 = kz + wk0 + 16 * sub;
        const float* wp = W + (size_t)k0 * ldw + nc + wn;
        #pragma unroll
        for (int j = 0; j < 4; ++j) wpre[sub][j] = wp[(size_t)j * ldw];
    }

    for (int it = 0; it < 8; ++it) {
        __syncthreads();
        #pragma unroll
        for (int ii = 0; ii < 4; ++ii) {
            int f = tid + 256 * ii, r = f >> 4, c4 = (f & 15) << 2;
            *(uint2*)&a_s[r][c4] =
                make_uint2(pack2(apre[ii].x, apre[ii].y), pack2(apre[ii].z, apre[ii].w));
        }
        #pragma unroll
        for (int sub = 0; sub < 4; ++sub) {
            int k0 = wk0 + 16 * sub;
            *(uint2*)&w_s[wn][k0] =
                make_uint2(pack2(wpre[sub][0], wpre[sub][1]),
                           pack2(wpre[sub][2], wpre[sub][3]));
        }
        __syncthreads();
        if (it + 1 < 8) {
            const int kb = kz + (it + 1) * 64;
            #pragma unroll
            for (int ii = 0; ii < 4; ++ii) {
                int f = tid + 256 * ii, r = f >> 4, c4 = (f & 15) << 2;
                apre[ii] = *(const float4*)&A[(size_t)(m0 + r) * DIM + kb + c4];
            }
            #pragma unroll
            for (int sub = 0; sub < 4; ++sub) {
                int k0 = kb + wk0 + 16 * sub;
                const float* wp = W + (size_t)k0 * ldw + nc + wn;
                #pragma unroll
                for (int j = 0; j < 4; ++j) wpre[sub][j] = wp[(size_t)j * ldw];
            }
        }
        #pragma unroll
        for (int kf = 0; kf < 2; ++kf) {
            bf16x8 af = *(const bf16x8*)&a_s[16 * wave + l15][kf * 32 + quad * 8];
            #pragma unroll
            for (int nt = 0; nt < 4; ++nt) {
                uint2 lo = *(const uint2*)&w_s[nt * 16 + l15][kf * 32 + quad * 8];
                uint2 hi = *(const uint2*)&w_s[nt * 16 + l15][kf * 32 + quad * 8 + 4];
                bf16x8 wf = mk_frag(lo.x, lo.y, hi.x, hi.y);
                acc[nt] = __builtin_amdgcn_mfma_f32_16x16x32_bf16(af, wf, acc[nt], 0, 0, 0);
            }
        }
    }
    // epilogue: C/D layout row=quad*4+reg, col=l15; atomicAdd into zeroed out
    const bool addb = (blockIdx.z == 0);
    #pragma unroll
    for (int nt = 0; nt < 4; ++nt)
        #pragma unroll
        for (int reg = 0; reg < 4; ++reg) {
            int row = m0 + 16 * wave + quad * 4 + reg;      // = b*4+q
            int col = n0 + nt * 16 + l15;
            float s = acc[nt][reg];
            if (VARIANT == 1) {
                atomicAdd(&o0[(size_t)row * DIM + col], s + (addb ? Bv[col] : 0.f));
            } else {
                int b = row >> 2, q = row & 3;
                if (col < 2048) {
                    int h = col >> 7, e = col & 127;
                    atomicAdd(&o0[((size_t)(b * 64 + h * 4 + q)) * 128 + e],
                              s + (addb ? b0p[col] : 0.f));
                } else if (col < 2176) {
                    int e = col - 2048;
                    atomicAdd(&o1[(size_t)row * 128 + e], s + (addb ? b1p[e] : 0.f));
                } else {
                    int e = col - 2176;
                    atomicAdd(&o2[(size_t)row * 128 + e], s + (addb ? b2p[e] : 0.f));
                }
            }
        }
}

// ---------------------------------------------------------------------------
// attn: flash-decoding partial, NO max subtraction (scores bounded ~|s|<8).
// grid (NCK=16, BATCH), block 256 = 4 waves; wave w owns hq rows 16w..16w+15.
// TWO-TILE-DEEP K/V register prefetch (sets 0/1, statically indexed, loop
// unrolled by 2). Loads for tile t are issued at t-2, giving 2 tile-periods
// of latency slack; the LDS-store wait for set A drains only to
// vmcnt(#setB outstanding), never 0 -- attacks the ~20K cy/tile exposed
// latency identified in R3 (35.7K cy/tile vs 16K BW floor).
// Bias prefetch stays 1-deep (16 small loads; saves 16 VGPR).
// LDS: 17408 + 17408 + 9216 = 44 KB. Plain partial stores.
// ---------------------------------------------------------------------------

#define PREFETCH_KV(tb_, kp_, vp_)                                            \
    do {                                                                      \
        _Pragma("unroll")                                                     \
        for (int i = 0; i < 8; ++i) {                                         \
            int f = tid + 256 * i;                                            \
            int row = f >> 5, e0 = (f & 31) << 2;                             \
            int kv = (tb_) + row;                                             \
            const float* pk = (kv < KVLEN - QL)                               \
                ? cachek + ((size_t)b * KVLEN + kv + QL) * HD + e0            \
                : kws + ((size_t)b * QL + (kv - (KVLEN - QL))) * HD + e0;     \
            kp_[i] = *(const float4*)pk;                                      \
        }                                                                     \
        _Pragma("unroll")                                                     \
        for (int i = 0; i < 8; ++i) {                                         \
            int kv0 = (tb_) + (vkq + 2 * i) * 4;                              \
            _Pragma("unroll")                                                 \
            for (int j = 0; j < 4; ++j) {                                     \
                int kv = kv0 + j;                                             \
                const float* pv = (kv < KVLEN - QL)                           \
                    ? cachev + ((size_t)b * KVLEN + kv + QL) * HD + ve        \
                    : vws + ((size_t)b * QL + (kv - (KVLEN - QL))) * HD + ve; \
                vp_[i][j] = *pv;                                              \
            }                                                                 \
        }                                                                     \
    } while (0)

#define PREFETCH_B(toff_)                                                     \
    do {                                                                      \
        _Pragma("unroll")                                                     \
        for (int nt = 0; nt < 4; ++nt)                                        \
            _Pragma("unroll")                                                 \
            for (int reg = 0; reg < 4; ++reg)                                 \
                bpre[nt * 4 + reg] = bptr[reg][(toff_) + nt * 16];            \
    } while (0)

#define STORE_LDS(kp_, vp_)                                                   \
    do {                                                                      \
        _Pragma("unroll")                                                     \
        for (int i = 0; i < 8; ++i) {                                         \
            int f = tid + 256 * i;                                            \
            int row = f >> 5, e0 = (f & 31) << 2;                             \
            *(uint2*)&k_s[row][e0] =                                          \
                make_uint2(pack2(kp_[i].x, kp_[i].y),                         \
                           pack2(kp_[i].z, kp_[i].w));                        \
        }                                                                     \
        _Pragma("unroll")                                                     \
        for (int i = 0; i < 8; ++i) {                                         \
            int kv0 = (vkq + 2 * i) * 4;                                      \
            *(uint2*)&v_sT[ve][kv0] =                                         \
                make_uint2(pack2(vp_[i][0], vp_[i][1]),                       \
                           pack2(vp_[i][2], vp_[i][3]));                      \
        }                                                                     \
    } while (0)

#define COMPUTE_TILE(bias_)                                                   \
    do {                                                                      \
        f32x4 sacc[4];                                                        \
        _Pragma("unroll")                                                     \
        for (int nt = 0; nt < 4; ++nt) sacc[nt] = (f32x4){0.f, 0.f, 0.f, 0.f};\
        __builtin_amdgcn_s_setprio(1);                                        \
        _Pragma("unroll")                                                     \
        for (int kf = 0; kf < 4; ++kf) {                                      \
            _Pragma("unroll")                                                 \
            for (int nt = 0; nt < 4; ++nt) {                                  \
                bf16x8 kfb = *(const bf16x8*)&k_s[nt * 16 + l15][kf * 32 + quad * 8]; \
                sacc[nt] = __builtin_amdgcn_mfma_f32_16x16x32_bf16(qf[kf], kfb, sacc[nt], 0, 0, 0); \
            }                                                                 \
        }                                                                     \
        __builtin_amdgcn_s_setprio(0);                                        \
        _Pragma("unroll")                                                     \
        for (int nt = 0; nt < 4; ++nt)                                        \
            _Pragma("unroll")                                                 \
            for (int reg = 0; reg < 4; ++reg) {                               \
                float s = sacc[nt][reg] * scale + bias_[nt * 4 + reg];        \
                float p = __expf(s);                                          \
                unsigned short pb = cvt_bf16(p);                              \
                lrow[reg] += bf16_to_f32(pb);                                 \
                p_s[wave][quad * 4 + reg][nt * 16 + l15] = pb;                \
            }                                                                 \
        __builtin_amdgcn_s_setprio(1);                                        \
        _Pragma("unroll")                                                     \
        for (int kfp = 0; kfp < 2; ++kfp) {                                   \
            uint2 plo = *(const uint2*)&p_s[wave][l15][kfp * 32 + quad * 8];  \
            uint2 phi = *(const uint2*)&p_s[wave][l15][kfp * 32 + quad * 8 + 4]; \
            bf16x8 pf = mk_frag(plo.x, plo.y, phi.x, phi.y);                  \
            _Pragma("unroll")                                                 \
            for (int n8 = 0; n8 < 8; ++n8) {                                  \
                uint2 vlo = *(const uint2*)&v_sT[n8 * 16 + l15][kfp * 32 + quad * 8]; \
                uint2 vhi = *(const uint2*)&v_sT[n8 * 16 + l15][kfp * 32 + quad * 8 + 4]; \
                bf16x8 vf = mk_frag(vlo.x, vlo.y, vhi.x, vhi.y);              \
                oa[n8] = __builtin_amdgcn_mfma_f32_16x16x32_bf16(pf, vf, oa[n8], 0, 0, 0); \
            }                                                                 \
        }                                                                     \
        __builtin_amdgcn_s_setprio(0);                                        \
    } while (0)

__global__ __launch_bounds__(256, 2) void attn_kernel(
    const float* __restrict__ qws, const float* __restrict__ kws,
    const float* __restrict__ vws,
    const float* __restrict__ cachek, const float* __restrict__ cachev,
    const float* __restrict__ abias,
    float* __restrict__ opart, float* __restrict__ lpart)
{
    const int ck = blockIdx.x;
    const int b  = blockIdx.y;
    const int tid = threadIdx.x;
    const int wave = tid >> 6, lane = tid & 63;
    const int l15 = lane & 15, quad = lane >> 4;
    const float scale = 0.08838834764831845f;   // 1/sqrt(128)

    __shared__ alignas(16) unsigned short k_s[KT][136];   // [kv][e], 272B rows
    __shared__ alignas(16) unsigned short v_sT[HD][68];   // [e][kv], 136B rows
    __shared__ alignas(16) unsigned short p_s[4][16][72]; // wave-private [m][kv]

    // ---- Q A-frags: m=l15 (row hq=16w+l15), k=e ----
    bf16x8 qf[4];
    {
        const float* qrow = qws + ((size_t)b * HQ + 16 * wave + l15) * HD;
        #pragma unroll
        for (int kf = 0; kf < 4; ++kf) {
            float4 f0 = *(const float4*)&qrow[kf * 32 + quad * 8];
            float4 f1 = *(const float4*)&qrow[kf * 32 + quad * 8 + 4];
            qf[kf] = mk_frag(pack2(f0.x, f0.y), pack2(f0.z, f0.w),
                             pack2(f1.x, f1.y), pack2(f1.z, f1.w));
        }
    }

    const int kbase0 = ck * CHUNK;
    // K staging coords: f = tid+256i -> row=f>>5, e0=(f&31)*4
    // V staging coords: e = tid&127, kv quad base = 4*((tid>>7)+2i)
    const int ve = tid & 127;
    const int vkq = (tid >> 7);

    // bias pointers (rows quad*4+reg of this wave's m-tile)
    const float* bptr[4];
    #pragma unroll
    for (int reg = 0; reg < 4; ++reg) {
        int hq = 16 * wave + quad * 4 + reg;
        int h = hq >> 2, q = hq & 3;
        bptr[reg] = abias + (((size_t)(b * NH + h)) * QL + q) * KVLEN + kbase0 + l15;
    }

    // two statically-named prefetch register sets (rule #20: no dynamic idx)
    float4 kpre0[8], kpre1[8];
    float vpre0[8][4], vpre1[8][4];
    float bpre[16];                      // 1-deep bias prefetch

    // ---- prologue: tile 0 -> set0, tile 1 -> set1, bias tile 0 ----
    PREFETCH_KV(kbase0, kpre0, vpre0);
    PREFETCH_KV(kbase0 + KT, kpre1, vpre1);
    PREFETCH_B(0);

    f32x4 oa[8];
    #pragma unroll
    for (int n8 = 0; n8 < 8; ++n8) oa[n8] = (f32x4){0.f, 0.f, 0.f, 0.f};
    float lrow[4] = {0.f, 0.f, 0.f, 0.f};

    for (int tt = 0; tt < NT; tt += 2) {
        // ---- even tile (tt): consume set0 ----
        {
            __syncthreads();            // prev tile's LDS reads done
            STORE_LDS(kpre0, vpre0);    // waits only set0's loads
            float bias[16];
            #pragma unroll
            for (int j = 0; j < 16; ++j) bias[j] = bpre[j];
            __syncthreads();
            if (tt + 2 < NT) PREFETCH_KV(kbase0 + (tt + 2) * KT, kpre0, vpre0);
            PREFETCH_B((tt + 1) * KT);  // bias for tile tt+1 (tt+1 <= 7 always)
            COMPUTE_TILE(bias);
        }
        // ---- odd tile (tt+1): consume set1 ----
        {
            __syncthreads();
            STORE_LDS(kpre1, vpre1);
            float bias[16];
            #pragma unroll
            for (int j = 0; j < 16; ++j) bias[j] = bpre[j];
            __syncthreads();
            if (tt + 3 < NT) PREFETCH_KV(kbase0 + (tt + 3) * KT, kpre1, vpre1);
            if (tt + 2 < NT) PREFETCH_B((tt + 2) * KT);
            COMPUTE_TILE(bias);
        }
    }
    // ---- reduce row sums over the 16 col-lanes ----
    #pragma unroll
    for (int reg = 0; reg < 4; ++reg) {
        float v = lrow[reg];
        v += __shfl_xor(v, 1);
        v += __shfl_xor(v, 2);
        v += __shfl_xor(v, 4);
        v += __shfl_xor(v, 8);
        lrow[reg] = v;
    }
    // ---- write unnormalized partial O + l (plain stores) ----
    const size_t obase = ((size_t)(b * NCK + ck)) * HQ * HD;
    #pragma unroll
    for (int n8 = 0; n8 < 8; ++n8)
        #pragma unroll
        for (int reg = 0; reg < 4; ++reg) {
            int hq = 16 * wave + quad * 4 + reg;
            int e = n8 * 16 + l15;
            opart[obase + (size_t)hq * HD + e] = oa[n8][reg];
        }
    if (l15 == 0) {
        #pragma unroll
        for (int reg = 0; reg < 4; ++reg) {
            int hq = 16 * wave + quad * 4 + reg;
            lpart[(size_t)(b * NCK + ck) * HQ + hq] = lrow[reg];
        }
    }
}

// ---------------------------------------------------------------------------
// combine: O = (sum_c opart) / (sum_c lpart); write [row=b*4+q][h*128+e].
// Also zeroes `out` (gemm1's atomic target) -- saves a memset dispatch;
// stream order guarantees completion before gemm1.
// ---------------------------------------------------------------------------
__global__ __launch_bounds__(128) void combine_kernel(
    const float* __restrict__ opart, const float* __restrict__ lpart,
    float* __restrict__ ored, float* __restrict__ outz)
{
    const int bh = blockIdx.x;
    const int b = bh >> 6, hq = bh & 63;
    const int e = threadIdx.x;
    outz[(size_t)bh * 128 + e] = 0.f;       // zero out (2048*128 = 262144)
    float lt = 0.f, ov = 0.f;
    #pragma unroll
    for (int c = 0; c < NCK; ++c) {
        lt += lpart[(b * NCK + c) * HQ + hq];
        ov += opart[((size_t)(b * NCK + c) * HQ + hq) * HD + e];
    }
    int h = hq >> 2, q = hq & 3;
    ored[(size_t)(b * QL + q) * DIM + h * HD + e] = ov / lt;
}

// ---------------------------------------------------------------------------
extern "C" void kernel_launch(void* const* d_in, const int* in_sizes, int n_in,
                              void* d_out, int out_size, void* d_ws, size_t ws_size,
                              hipStream_t stream)
{
    const float* x   = (const float*)d_in[0];
    const float* ab  = (const float*)d_in[1];
    const float* cK  = (const float*)d_in[2];
    const float* cV  = (const float*)d_in[3];
    const float* wq  = (const float*)d_in[4];
    const float* bq  = (const float*)d_in[5];
    const float* wk  = (const float*)d_in[6];
    const float* bk  = (const float*)d_in[7];
    const float* wv  = (const float*)d_in[8];
    const float* bv  = (const float*)d_in[9];
    const float* wo  = (const float*)d_in[10];
    const float* bo  = (const float*)d_in[11];
    float* out = (float*)d_out;

    // workspace (floats), ~19 MB
    float* ws   = (float*)d_ws;
    float* wsq  = ws;                    // 32*64*128  = 262144
    float* wsk  = wsq + 262144;          // 16384
    float* wsv  = wsk + 16384;           // 16384
    float* wsop = wsv + 16384;           // 32*16*64*128 = 4194304 (plain stores)
    float* wsl  = wsop + 4194304;        // 32768 (plain stores)
    float* wsor = wsl + 32768;           // 262144 (written fully by combine)

    // memset only the gemm0 atomic targets (attn partials are plain stores)
    hipMemsetAsync(ws, 0, (size_t)(262144 + 16384 + 16384) * sizeof(float),
                   stream);

    gemm_kernel<0><<<dim3(36, 2, 4), 256, 0, stream>>>(
        x, wq, wk, wv, bq, bk, bv, wsq, wsk, wsv);
    attn_kernel<<<dim3(NCK, BATCH), 256, 0, stream>>>(
        wsq, wsk, wsv, cK, cV, ab, wsop, wsl);
    combine_kernel<<<BATCH * HQ, 128, 0, stream>>>(wsop, wsl, wsor, out);
    gemm_kernel<1><<<dim3(32, 2, 4), 256, 0, stream>>>(
        wsor, wo, nullptr, nullptr, bo, nullptr, nullptr, out, nullptr, nullptr);
}

// Round 6
// 398.592 us; speedup vs baseline: 1.0921x; 1.0921x over previous
//
#include <hip/hip_runtime.h>
#include <cstddef>
#include <cstdint>

#define BATCH 32
#define QL 4
#define DIM 2048
#define NH 16
#define HD 128
#define KVLEN 8192
#define HQ 64          // NH*QL
#define CHUNK 512
#define NCK 16         // KVLEN / CHUNK
#define KT 64          // kv rows per tile
#define NT 8           // CHUNK / KT

typedef __attribute__((ext_vector_type(8))) short bf16x8;   // 8 bf16 (4 VGPRs)
typedef __attribute__((ext_vector_type(4))) float f32x4;    // MFMA C/D

__device__ __forceinline__ unsigned short cvt_bf16(float f) {
    unsigned int u = __builtin_bit_cast(unsigned int, f);
    u += 0x7fffu + ((u >> 16) & 1u);            // RNE
    return (unsigned short)(u >> 16);
}
__device__ __forceinline__ unsigned int pack2(float a, float b) {
    return (unsigned int)cvt_bf16(a) | ((unsigned int)cvt_bf16(b) << 16);
}
__device__ __forceinline__ float bf16_to_f32(unsigned short s) {
    unsigned int u = ((unsigned int)s) << 16;
    return __builtin_bit_cast(float, u);
}
__device__ __forceinline__ bf16x8 mk_frag(unsigned int a, unsigned int b,
                                          unsigned int c, unsigned int d) {
    unsigned int t[4] = {a, b, c, d};
    return *(const bf16x8*)t;
}

// ---------------------------------------------------------------------------
// GEMM core: C[128,N] = A[128,K=2048] @ W, split-K x4 (blockIdx.z), each
// split does K=512 in 8 BK=64 iters; epilogue fp32 atomicAdd into zeroed
// output, bias added only by the z==0 split. (R3 verified: split-K 8 vs 4
// perf-neutral; atomics are not the hidden cost.)
// ---------------------------------------------------------------------------
template<int VARIANT>
__global__ __launch_bounds__(256) void gemm_kernel(
    const float* __restrict__ A,
    const float* __restrict__ w0p, const float* __restrict__ w1p,
    const float* __restrict__ w2p,
    const float* __restrict__ b0p, const float* __restrict__ b1p,
    const float* __restrict__ b2p,
    float* __restrict__ o0, float* __restrict__ o1, float* __restrict__ o2)
{
    const int n0 = blockIdx.x * 64;
    const int m0 = blockIdx.y * 64;
    const int kz = blockIdx.z * 512;        // split-K base
    const int tid = threadIdx.x;
    const int wave = tid >> 6, lane = tid & 63;
    const int l15 = lane & 15, quad = lane >> 4;

    const float* W; const float* Bv; int ldw, nc;
    if (VARIANT == 0) {
        if (n0 >= 2176)      { W = w2p; Bv = b2p; ldw = 128;  nc = n0 - 2176; }
        else if (n0 >= 2048) { W = w1p; Bv = b1p; ldw = 128;  nc = n0 - 2048; }
        else                 { W = w0p; Bv = b0p; ldw = 2048; nc = n0; }
    } else { W = w0p; Bv = b0p; ldw = 2048; nc = n0; }

    __shared__ alignas(16) unsigned short a_s[64][72];   // [m][k], 144B rows
    __shared__ alignas(16) unsigned short w_s[64][68];   // [n][k], 136B rows

    const int wn = tid & 63;            // W: n within tile
    const int wk0 = (tid >> 6) * 4;     // W: k quad base (+16*sub)

    f32x4 acc[4];
    #pragma unroll
    for (int nt = 0; nt < 4; ++nt) acc[nt] = (f32x4){0.f, 0.f, 0.f, 0.f};

    float4 apre[4];
    float wpre[4][4];                   // [sub][j]

    #pragma unroll
    for (int ii = 0; ii < 4; ++ii) {
        int f = tid + 256 * ii, r = f >> 4, c4 = (f & 15) << 2;
        apre[ii] = *(const float4*)&A[(size_t)(m0 + r) * DIM + kz + c4];
    }
    #pragma unroll
    for (int sub = 0; sub < 4; ++sub) {
        int k0 = kz + wk0 + 16 * sub;
        const float* wp = W + (size_t)k0 * ldw + nc + wn;
        #pragma unroll
        for (int j = 0; j < 4; ++j) wpre[sub][j] = wp[(size_t)j * ldw];
    }

    for (int it = 0; it < 8; ++it) {
        __syncthreads();
        #pragma unroll
        for (int ii = 0; ii < 4; ++ii) {
            int f = tid + 256 * ii, r = f >> 4, c4 = (f & 15) << 2;
            *(uint2*)&a_s[r][c4] =
                make_uint2(pack2(apre[ii].x, apre[ii].y), pack2(apre[ii].z, apre[ii].w));
        }
        #pragma unroll
        for (int sub = 0; sub < 4; ++sub) {
            int k0 = wk0 + 16 * sub;
            *(uint2*)&w_s[wn][k0] =
                make_uint2(pack2(wpre[sub][0], wpre[sub][1]),
                           pack2(wpre[sub][2], wpre[sub][3]));
        }
        __syncthreads();
        if (it + 1 < 8) {
            const int kb = kz + (it + 1) * 64;
            #pragma unroll
            for (int ii = 0; ii < 4; ++ii) {
                int f = tid + 256 * ii, r = f >> 4, c4 = (f & 15) << 2;
                apre[ii] = *(const float4*)&A[(size_t)(m0 + r) * DIM + kb + c4];
            }
            #pragma unroll
            for (int sub = 0; sub < 4; ++sub) {
                int k0 = kb + wk0 + 16 * sub;
                const float* wp = W + (size_t)k0 * ldw + nc + wn;
                #pragma unroll
                for (int j = 0; j < 4; ++j) wpre[sub][j] = wp[(size_t)j * ldw];
            }
        }
        #pragma unroll
        for (int kf = 0; kf < 2; ++kf) {
            bf16x8 af = *(const bf16x8*)&a_s[16 * wave + l15][kf * 32 + quad * 8];
            #pragma unroll
            for (int nt = 0; nt < 4; ++nt) {
                uint2 lo = *(const uint2*)&w_s[nt * 16 + l15][kf * 32 + quad * 8];
                uint2 hi = *(const uint2*)&w_s[nt * 16 + l15][kf * 32 + quad * 8 + 4];
                bf16x8 wf = mk_frag(lo.x, lo.y, hi.x, hi.y);
                acc[nt] = __builtin_amdgcn_mfma_f32_16x16x32_bf16(af, wf, acc[nt], 0, 0, 0);
            }
        }
    }
    const bool addb = (blockIdx.z == 0);
    #pragma unroll
    for (int nt = 0; nt < 4; ++nt)
        #pragma unroll
        for (int reg = 0; reg < 4; ++reg) {
            int row = m0 + 16 * wave + quad * 4 + reg;      // = b*4+q
            int col = n0 + nt * 16 + l15;
            float s = acc[nt][reg];
            if (VARIANT == 1) {
                atomicAdd(&o0[(size_t)row * DIM + col], s + (addb ? Bv[col] : 0.f));
            } else {
                int b = row >> 2, q = row & 3;
                if (col < 2048) {
                    int h = col >> 7, e = col & 127;
                    atomicAdd(&o0[((size_t)(b * 64 + h * 4 + q)) * 128 + e],
                              s + (addb ? b0p[col] : 0.f));
                } else if (col < 2176) {
                    int e = col - 2048;
                    atomicAdd(&o1[(size_t)row * 128 + e], s + (addb ? b1p[e] : 0.f));
                } else {
                    int e = col - 2176;
                    atomicAdd(&o2[(size_t)row * 128 + e], s + (addb ? b2p[e] : 0.f));
                }
            }
        }
}

// ---------------------------------------------------------------------------
// attn: flash-decoding partial, NO max subtraction (scores bounded ~|s|<8).
// grid (NCK=16, BATCH), block 256 = 4 waves; wave w owns hq rows 16w..16w+15.
// R6: LDS DOUBLE-BUFFER pipeline, ONE barrier per tile. Schedule per tile:
//   sync -> COMPUTE(bufA) -> STORE(bufB) [vmcnt wait HERE, after compute]
//        -> issue PREFETCH(t+2)
// Loads for tile t+1 are issued before compute of tile t, so their HBM
// service (~16K cy/CU at BW fair-share) overlaps the compute phase; the
// pipe keeps outstanding loads except during the brief pack/store window.
// Attacks R3's convoy (35.7K cy/tile measured vs 16K BW floor) with the
// SAME register footprint as R3 (R5's 2-deep register scheme spilled:
// VGPR capped 128, +90MB scratch traffic, 157us).
// LDS: 2*17408 (K) + 2*17408 (V) + 9216 (P) = 78848 B -> 2 blocks/CU.
// ---------------------------------------------------------------------------

#define PREFETCH_KV(tb_)                                                      \
    do {                                                                      \
        _Pragma("unroll")                                                     \
        for (int i = 0; i < 8; ++i) {                                         \
            int f = tid + 256 * i;                                            \
            int row = f >> 5, e0 = (f & 31) << 2;                             \
            int kv = (tb_) + row;                                             \
            const float* pk = (kv < KVLEN - QL)                               \
                ? cachek + ((size_t)b * KVLEN + kv + QL) * HD + e0            \
                : kws + ((size_t)b * QL + (kv - (KVLEN - QL))) * HD + e0;     \
            kpre[i] = *(const float4*)pk;                                     \
        }                                                                     \
        _Pragma("unroll")                                                     \
        for (int i = 0; i < 8; ++i) {                                         \
            int kv0 = (tb_) + (vkq + 2 * i) * 4;                              \
            _Pragma("unroll")                                                 \
            for (int j = 0; j < 4; ++j) {                                     \
                int kv = kv0 + j;                                             \
                const float* pv = (kv < KVLEN - QL)                           \
                    ? cachev + ((size_t)b * KVLEN + kv + QL) * HD + ve        \
                    : vws + ((size_t)b * QL + (kv - (KVLEN - QL))) * HD + ve; \
                vpre[i][j] = *pv;                                             \
            }                                                                 \
        }                                                                     \
    } while (0)

#define PREFETCH_B(toff_)                                                     \
    do {                                                                      \
        _Pragma("unroll")                                                     \
        for (int nt = 0; nt < 4; ++nt)                                        \
            _Pragma("unroll")                                                 \
            for (int reg = 0; reg < 4; ++reg)                                 \
                bpre[nt * 4 + reg] = bptr[reg][(toff_) + nt * 16];            \
    } while (0)

#define STORE_LDS(ks_, vs_)                                                   \
    do {                                                                      \
        _Pragma("unroll")                                                     \
        for (int i = 0; i < 8; ++i) {                                         \
            int f = tid + 256 * i;                                            \
            int row = f >> 5, e0 = (f & 31) << 2;                             \
            *(uint2*)&ks_[row][e0] =                                          \
                make_uint2(pack2(kpre[i].x, kpre[i].y),                       \
                           pack2(kpre[i].z, kpre[i].w));                      \
        }                                                                     \
        _Pragma("unroll")                                                     \
        for (int i = 0; i < 8; ++i) {                                         \
            int kv0 = (vkq + 2 * i) * 4;                                      \
            *(uint2*)&vs_[ve][kv0] =                                          \
                make_uint2(pack2(vpre[i][0], vpre[i][1]),                     \
                           pack2(vpre[i][2], vpre[i][3]));                    \
        }                                                                     \
    } while (0)

#define COMPUTE_TILE(bias_, ks_, vs_)                                         \
    do {                                                                      \
        f32x4 sacc[4];                                                        \
        _Pragma("unroll")                                                     \
        for (int nt = 0; nt < 4; ++nt) sacc[nt] = (f32x4){0.f, 0.f, 0.f, 0.f};\
        __builtin_amdgcn_s_setprio(1);                                        \
        _Pragma("unroll")                                                     \
        for (int kf = 0; kf < 4; ++kf) {                                      \
            _Pragma("unroll")                                                 \
            for (int nt = 0; nt < 4; ++nt) {                                  \
                bf16x8 kfb = *(const bf16x8*)&ks_[nt * 16 + l15][kf * 32 + quad * 8]; \
                sacc[nt] = __builtin_amdgcn_mfma_f32_16x16x32_bf16(qf[kf], kfb, sacc[nt], 0, 0, 0); \
            }                                                                 \
        }                                                                     \
        __builtin_amdgcn_s_setprio(0);                                        \
        _Pragma("unroll")                                                     \
        for (int nt = 0; nt < 4; ++nt)                                        \
            _Pragma("unroll")                                                 \
            for (int reg = 0; reg < 4; ++reg) {                               \
                float s = sacc[nt][reg] * scale + bias_[nt * 4 + reg];        \
                float p = __expf(s);                                          \
                unsigned short pb = cvt_bf16(p);                              \
                lrow[reg] += bf16_to_f32(pb);                                 \
                p_s[wave][quad * 4 + reg][nt * 16 + l15] = pb;                \
            }                                                                 \
        __builtin_amdgcn_s_setprio(1);                                        \
        _Pragma("unroll")                                                     \
        for (int kfp = 0; kfp < 2; ++kfp) {                                   \
            uint2 plo = *(const uint2*)&p_s[wave][l15][kfp * 32 + quad * 8];  \
            uint2 phi = *(const uint2*)&p_s[wave][l15][kfp * 32 + quad * 8 + 4]; \
            bf16x8 pf = mk_frag(plo.x, plo.y, phi.x, phi.y);                  \
            _Pragma("unroll")                                                 \
            for (int n8 = 0; n8 < 8; ++n8) {                                  \
                uint2 vlo = *(const uint2*)&vs_[n8 * 16 + l15][kfp * 32 + quad * 8]; \
                uint2 vhi = *(const uint2*)&vs_[n8 * 16 + l15][kfp * 32 + quad * 8 + 4]; \
                bf16x8 vf = mk_frag(vlo.x, vlo.y, vhi.x, vhi.y);              \
                oa[n8] = __builtin_amdgcn_mfma_f32_16x16x32_bf16(pf, vf, oa[n8], 0, 0, 0); \
            }                                                                 \
        }                                                                     \
        __builtin_amdgcn_s_setprio(0);                                        \
    } while (0)

__global__ __launch_bounds__(256, 2) void attn_kernel(
    const float* __restrict__ qws, const float* __restrict__ kws,
    const float* __restrict__ vws,
    const float* __restrict__ cachek, const float* __restrict__ cachev,
    const float* __restrict__ abias,
    float* __restrict__ opart, float* __restrict__ lpart)
{
    const int ck = blockIdx.x;
    const int b  = blockIdx.y;
    const int tid = threadIdx.x;
    const int wave = tid >> 6, lane = tid & 63;
    const int l15 = lane & 15, quad = lane >> 4;
    const float scale = 0.08838834764831845f;   // 1/sqrt(128)

    // double-buffered K/V tiles
    __shared__ alignas(16) unsigned short k_s0[KT][136];   // [kv][e], 272B rows
    __shared__ alignas(16) unsigned short k_s1[KT][136];
    __shared__ alignas(16) unsigned short v_s0[HD][68];    // [e][kv], 136B rows
    __shared__ alignas(16) unsigned short v_s1[HD][68];
    __shared__ alignas(16) unsigned short p_s[4][16][72];  // wave-private [m][kv]

    // ---- Q A-frags: m=l15 (row hq=16w+l15), k=e ----
    bf16x8 qf[4];
    {
        const float* qrow = qws + ((size_t)b * HQ + 16 * wave + l15) * HD;
        #pragma unroll
        for (int kf = 0; kf < 4; ++kf) {
            float4 f0 = *(const float4*)&qrow[kf * 32 + quad * 8];
            float4 f1 = *(const float4*)&qrow[kf * 32 + quad * 8 + 4];
            qf[kf] = mk_frag(pack2(f0.x, f0.y), pack2(f0.z, f0.w),
                             pack2(f1.x, f1.y), pack2(f1.z, f1.w));
        }
    }

    const int kbase0 = ck * CHUNK;
    // K staging coords: f = tid+256i -> row=f>>5, e0=(f&31)*4
    // V staging coords: e = tid&127, kv quad base = 4*((tid>>7)+2i)
    const int ve = tid & 127;
    const int vkq = (tid >> 7);

    // bias pointers (rows quad*4+reg of this wave's m-tile)
    const float* bptr[4];
    #pragma unroll
    for (int reg = 0; reg < 4; ++reg) {
        int hq = 16 * wave + quad * 4 + reg;
        int h = hq >> 2, q = hq & 3;
        bptr[reg] = abias + (((size_t)(b * NH + h)) * QL + q) * KVLEN + kbase0 + l15;
    }

    float4 kpre[8];
    float vpre[8][4];
    float bpre[16];                      // 1-deep bias prefetch

    // ---- prologue: t0 -> buf0 (stores before first barrier are safe);
    //      then issue t1 loads so they fly across tile 0's compute ----
    PREFETCH_KV(kbase0);
    STORE_LDS(k_s0, v_s0);
    PREFETCH_KV(kbase0 + KT);
    PREFETCH_B(0);

    f32x4 oa[8];
    #pragma unroll
    for (int n8 = 0; n8 < 8; ++n8) oa[n8] = (f32x4){0.f, 0.f, 0.f, 0.f};
    float lrow[4] = {0.f, 0.f, 0.f, 0.f};

    for (int tt = 0; tt < NT; tt += 2) {
        // ---- even tile tt: compute buf0, store t+1 into buf1 ----
        {
            __syncthreads();            // buf0 stores visible; buf1 reads done
            float bias[16];
            #pragma unroll
            for (int j = 0; j < 16; ++j) bias[j] = bpre[j];
            PREFETCH_B((tt + 1) * KT);  // bias t+1 (tt+1 <= 7 always)
            COMPUTE_TILE(bias, k_s0, v_s0);
            STORE_LDS(k_s1, v_s1);      // waits t+1 loads (flew over compute)
            if (tt + 2 < NT) PREFETCH_KV(kbase0 + (tt + 2) * KT);
        }
        // ---- odd tile tt+1: compute buf1, store t+2 into buf0 ----
        {
            __syncthreads();
            float bias[16];
            #pragma unroll
            for (int j = 0; j < 16; ++j) bias[j] = bpre[j];
            if (tt + 2 < NT) PREFETCH_B((tt + 2) * KT);
            COMPUTE_TILE(bias, k_s1, v_s1);
            if (tt + 2 < NT) {
                STORE_LDS(k_s0, v_s0);
                if (tt + 3 < NT) PREFETCH_KV(kbase0 + (tt + 3) * KT);
            }
        }
    }
    // ---- reduce row sums over the 16 col-lanes ----
    #pragma unroll
    for (int reg = 0; reg < 4; ++reg) {
        float v = lrow[reg];
        v += __shfl_xor(v, 1);
        v += __shfl_xor(v, 2);
        v += __shfl_xor(v, 4);
        v += __shfl_xor(v, 8);
        lrow[reg] = v;
    }
    // ---- write unnormalized partial O + l (plain stores) ----
    const size_t obase = ((size_t)(b * NCK + ck)) * HQ * HD;
    #pragma unroll
    for (int n8 = 0; n8 < 8; ++n8)
        #pragma unroll
        for (int reg = 0; reg < 4; ++reg) {
            int hq = 16 * wave + quad * 4 + reg;
            int e = n8 * 16 + l15;
            opart[obase + (size_t)hq * HD + e] = oa[n8][reg];
        }
    if (l15 == 0) {
        #pragma unroll
        for (int reg = 0; reg < 4; ++reg) {
            int hq = 16 * wave + quad * 4 + reg;
            lpart[(size_t)(b * NCK + ck) * HQ + hq] = lrow[reg];
        }
    }
}

// ---------------------------------------------------------------------------
// combine: O = (sum_c opart) / (sum_c lpart); write [row=b*4+q][h*128+e].
// Also zeroes `out` (gemm1's atomic target).
// ---------------------------------------------------------------------------
__global__ __launch_bounds__(128) void combine_kernel(
    const float* __restrict__ opart, const float* __restrict__ lpart,
    float* __restrict__ ored, float* __restrict__ outz)
{
    const int bh = blockIdx.x;
    const int b = bh >> 6, hq = bh & 63;
    const int e = threadIdx.x;
    outz[(size_t)bh * 128 + e] = 0.f;       // zero out (2048*128 = 262144)
    float lt = 0.f, ov = 0.f;
    #pragma unroll
    for (int c = 0; c < NCK; ++c) {
        lt += lpart[(b * NCK + c) * HQ + hq];
        ov += opart[((size_t)(b * NCK + c) * HQ + hq) * HD + e];
    }
    int h = hq >> 2, q = hq & 3;
    ored[(size_t)(b * QL + q) * DIM + h * HD + e] = ov / lt;
}

// ---------------------------------------------------------------------------
extern "C" void kernel_launch(void* const* d_in, const int* in_sizes, int n_in,
                              void* d_out, int out_size, void* d_ws, size_t ws_size,
                              hipStream_t stream)
{
    const float* x   = (const float*)d_in[0];
    const float* ab  = (const float*)d_in[1];
    const float* cK  = (const float*)d_in[2];
    const float* cV  = (const float*)d_in[3];
    const float* wq  = (const float*)d_in[4];
    const float* bq  = (const float*)d_in[5];
    const float* wk  = (const float*)d_in[6];
    const float* bk  = (const float*)d_in[7];
    const float* wv  = (const float*)d_in[8];
    const float* bv  = (const float*)d_in[9];
    const float* wo  = (const float*)d_in[10];
    const float* bo  = (const float*)d_in[11];
    float* out = (float*)d_out;

    // workspace (floats), ~19 MB
    float* ws   = (float*)d_ws;
    float* wsq  = ws;                    // 32*64*128  = 262144
    float* wsk  = wsq + 262144;          // 16384
    float* wsv  = wsk + 16384;           // 16384
    float* wsop = wsv + 16384;           // 32*16*64*128 = 4194304 (plain stores)
    float* wsl  = wsop + 4194304;        // 32768 (plain stores)
    float* wsor = wsl + 32768;           // 262144 (written fully by combine)

    // memset only the gemm0 atomic targets (attn partials are plain stores)
    hipMemsetAsync(ws, 0, (size_t)(262144 + 16384 + 16384) * sizeof(float),
                   stream);

    gemm_kernel<0><<<dim3(36, 2, 4), 256, 0, stream>>>(
        x, wq, wk, wv, bq, bk, bv, wsq, wsk, wsv);
    attn_kernel<<<dim3(NCK, BATCH), 256, 0, stream>>>(
        wsq, wsk, wsv, cK, cV, ab, wsop, wsl);
    combine_kernel<<<BATCH * HQ, 128, 0, stream>>>(wsop, wsl, wsor, out);
    gemm_kernel<1><<<dim3(32, 2, 4), 256, 0, stream>>>(
        wsor, wo, nullptr, nullptr, bo, nullptr, nullptr, out, nullptr, nullptr);
}

// Round 7
// 395.989 us; speedup vs baseline: 1.0993x; 1.0066x over previous
//
#include <hip/hip_runtime.h>
#include <cstddef>
#include <cstdint>

#define BATCH 32
#define QL 4
#define DIM 2048
#define NH 16
#define HD 128
#define KVLEN 8192
#define HQ 64          // NH*QL
#define CHUNK 512
#define NCK 16         // KVLEN / CHUNK
#define KT 64          // kv rows per tile
#define NT 8           // CHUNK / KT

typedef __attribute__((ext_vector_type(8))) short bf16x8;   // 8 bf16 (4 VGPRs)
typedef __attribute__((ext_vector_type(4))) float f32x4;    // MFMA C/D

__device__ __forceinline__ unsigned short cvt_bf16(float f) {
    unsigned int u = __builtin_bit_cast(unsigned int, f);
    u += 0x7fffu + ((u >> 16) & 1u);            // RNE
    return (unsigned short)(u >> 16);
}
__device__ __forceinline__ unsigned int pack2(float a, float b) {
    return (unsigned int)cvt_bf16(a) | ((unsigned int)cvt_bf16(b) << 16);
}
__device__ __forceinline__ float bf16_to_f32(unsigned short s) {
    unsigned int u = ((unsigned int)s) << 16;
    return __builtin_bit_cast(float, u);
}
__device__ __forceinline__ bf16x8 mk_frag(unsigned int a, unsigned int b,
                                          unsigned int c, unsigned int d) {
    unsigned int t[4] = {a, b, c, d};
    return *(const bf16x8*)t;
}

// ---------------------------------------------------------------------------
// GEMM core: C[128,N] = A[128,K=2048] @ W, split-K x4 (blockIdx.z), each
// split does K=512 in 8 BK=64 iters; epilogue fp32 atomicAdd into zeroed
// output, bias added only by the z==0 split.
// variant 0: N=2304 fused QKV -> qws/kws/vws scatter with bq/bk/bv.
//            Also zeroes `zout` (gemm1's atomic target) at entry -- kills
//            the second memset dispatch; stream order covers gemm1.
// variant 1: N=2048 -> out with bo. A is the attn accumulator oacc; the
//            flash-decoding normalize (A = oacc/lacc) is fused into the
//            A-prefetch (lacc passed via w1p). Combine kernel is GONE.
// ---------------------------------------------------------------------------
template<int VARIANT>
__global__ __launch_bounds__(256) void gemm_kernel(
    const float* __restrict__ A,
    const float* __restrict__ w0p, const float* __restrict__ w1p,
    const float* __restrict__ w2p,
    const float* __restrict__ b0p, const float* __restrict__ b1p,
    const float* __restrict__ b2p,
    float* __restrict__ o0, float* __restrict__ o1, float* __restrict__ o2,
    float* __restrict__ zout)
{
    const int n0 = blockIdx.x * 64;
    const int m0 = blockIdx.y * 64;
    const int kz = blockIdx.z * 512;        // split-K base
    const int tid = threadIdx.x;
    const int wave = tid >> 6, lane = tid & 63;
    const int l15 = lane & 15, quad = lane >> 4;

    if (VARIANT == 0) {
        // zero gemm1's atomic target (262144 floats over 288 blocks x 256 thr)
        int gbid = (blockIdx.z * 2 + blockIdx.y) * 36 + blockIdx.x;
        int base = gbid * 256 + tid;
        #pragma unroll
        for (int i = 0; i < 4; ++i) {
            int idx = base + 73728 * i;
            if (idx < 262144) zout[idx] = 0.f;
        }
    }

    const float* W; const float* Bv; int ldw, nc;
    if (VARIANT == 0) {
        if (n0 >= 2176)      { W = w2p; Bv = b2p; ldw = 128;  nc = n0 - 2176; }
        else if (n0 >= 2048) { W = w1p; Bv = b1p; ldw = 128;  nc = n0 - 2048; }
        else                 { W = w0p; Bv = b0p; ldw = 2048; nc = n0; }
    } else { W = w0p; Bv = b0p; ldw = 2048; nc = n0; }
    const float* Lp = w1p;              // VARIANT 1: lacc (normalizer)

    __shared__ alignas(16) unsigned short a_s[64][72];   // [m][k], 144B rows
    __shared__ alignas(16) unsigned short w_s[64][68];   // [n][k], 136B rows

    const int wn = tid & 63;            // W: n within tile
    const int wk0 = (tid >> 6) * 4;     // W: k quad base (+16*sub)

    f32x4 acc[4];
    #pragma unroll
    for (int nt = 0; nt < 4; ++nt) acc[nt] = (f32x4){0.f, 0.f, 0.f, 0.f};

    float4 apre[4];
    float wpre[4][4];                   // [sub][j]

    #pragma unroll
    for (int ii = 0; ii < 4; ++ii) {
        int f = tid + 256 * ii, r = f >> 4, c4 = (f & 15) << 2;
        int row = m0 + r, cc = kz + c4;
        if (VARIANT == 1) {
            int bb = row >> 2, q = row & 3, h = cc >> 7, e0 = cc & 127;
            int hq = h * 4 + q;
            float4 v = *(const float4*)&A[((size_t)(bb * 64 + hq)) * 128 + e0];
            float linv = 1.0f / Lp[bb * 64 + hq];
            apre[ii] = make_float4(v.x * linv, v.y * linv, v.z * linv, v.w * linv);
        } else {
            apre[ii] = *(const float4*)&A[(size_t)row * DIM + cc];
        }
    }
    #pragma unroll
    for (int sub = 0; sub < 4; ++sub) {
        int k0 = kz + wk0 + 16 * sub;
        const float* wp = W + (size_t)k0 * ldw + nc + wn;
        #pragma unroll
        for (int j = 0; j < 4; ++j) wpre[sub][j] = wp[(size_t)j * ldw];
    }

    for (int it = 0; it < 8; ++it) {
        __syncthreads();
        #pragma unroll
        for (int ii = 0; ii < 4; ++ii) {
            int f = tid + 256 * ii, r = f >> 4, c4 = (f & 15) << 2;
            *(uint2*)&a_s[r][c4] =
                make_uint2(pack2(apre[ii].x, apre[ii].y), pack2(apre[ii].z, apre[ii].w));
        }
        #pragma unroll
        for (int sub = 0; sub < 4; ++sub) {
            int k0 = wk0 + 16 * sub;
            *(uint2*)&w_s[wn][k0] =
                make_uint2(pack2(wpre[sub][0], wpre[sub][1]),
                           pack2(wpre[sub][2], wpre[sub][3]));
        }
        __syncthreads();
        if (it + 1 < 8) {
            const int kb = kz + (it + 1) * 64;
            #pragma unroll
            for (int ii = 0; ii < 4; ++ii) {
                int f = tid + 256 * ii, r = f >> 4, c4 = (f & 15) << 2;
                int row = m0 + r, cc = kb + c4;
                if (VARIANT == 1) {
                    int bb = row >> 2, q = row & 3, h = cc >> 7, e0 = cc & 127;
                    int hq = h * 4 + q;
                    float4 v = *(const float4*)&A[((size_t)(bb * 64 + hq)) * 128 + e0];
                    float linv = 1.0f / Lp[bb * 64 + hq];
                    apre[ii] = make_float4(v.x * linv, v.y * linv, v.z * linv, v.w * linv);
                } else {
                    apre[ii] = *(const float4*)&A[(size_t)row * DIM + cc];
                }
            }
            #pragma unroll
            for (int sub = 0; sub < 4; ++sub) {
                int k0 = kb + wk0 + 16 * sub;
                const float* wp = W + (size_t)k0 * ldw + nc + wn;
                #pragma unroll
                for (int j = 0; j < 4; ++j) wpre[sub][j] = wp[(size_t)j * ldw];
            }
        }
        #pragma unroll
        for (int kf = 0; kf < 2; ++kf) {
            bf16x8 af = *(const bf16x8*)&a_s[16 * wave + l15][kf * 32 + quad * 8];
            #pragma unroll
            for (int nt = 0; nt < 4; ++nt) {
                uint2 lo = *(const uint2*)&w_s[nt * 16 + l15][kf * 32 + quad * 8];
                uint2 hi = *(const uint2*)&w_s[nt * 16 + l15][kf * 32 + quad * 8 + 4];
                bf16x8 wf = mk_frag(lo.x, lo.y, hi.x, hi.y);
                acc[nt] = __builtin_amdgcn_mfma_f32_16x16x32_bf16(af, wf, acc[nt], 0, 0, 0);
            }
        }
    }
    const bool addb = (blockIdx.z == 0);
    #pragma unroll
    for (int nt = 0; nt < 4; ++nt)
        #pragma unroll
        for (int reg = 0; reg < 4; ++reg) {
            int row = m0 + 16 * wave + quad * 4 + reg;      // = b*4+q
            int col = n0 + nt * 16 + l15;
            float s = acc[nt][reg];
            if (VARIANT == 1) {
                atomicAdd(&o0[(size_t)row * DIM + col], s + (addb ? Bv[col] : 0.f));
            } else {
                int b = row >> 2, q = row & 3;
                if (col < 2048) {
                    int h = col >> 7, e = col & 127;
                    atomicAdd(&o0[((size_t)(b * 64 + h * 4 + q)) * 128 + e],
                              s + (addb ? b0p[col] : 0.f));
                } else if (col < 2176) {
                    int e = col - 2048;
                    atomicAdd(&o1[(size_t)row * 128 + e], s + (addb ? b1p[e] : 0.f));
                } else {
                    int e = col - 2176;
                    atomicAdd(&o2[(size_t)row * 128 + e], s + (addb ? b2p[e] : 0.f));
                }
            }
        }
}

// ---------------------------------------------------------------------------
// attn: flash-decoding partial, NO max subtraction (scores bounded ~|s|<8).
// grid (NCK=16, BATCH), block 256 = 4 waves; wave w owns hq rows 16w..16w+15.
// R7 changes vs R6:
//  (a) INTERLEAVED store/prefetch: store K(t+1) [drains K's vmcnt while V's
//      32 loads stay outstanding] -> issue K(t+2) -> store V(t+1) [K(t+2)
//      in flight] -> issue V(t+2). The memory pipe never fully drains;
//      zero extra registers (R5's 2-deep reg scheme spilled).
//  (b) Epilogue atomically accumulates O/l partials across the 16 chunks of
//      each batch into oacc[b][hq][e] / lacc[b][hq] (order-invariant sums) --
//      the combine kernel is deleted; gemm1 normalizes on A-load.
// LDS: 2*17408 (K) + 2*17408 (V) + 9216 (P) = 78848 B -> 2 blocks/CU.
// attn is ~90% of the ~3.1 TB/s fabric read ceiling (335 MB delivered).
// ---------------------------------------------------------------------------

#define PREFETCH_K(tb_)                                                       \
    do {                                                                      \
        _Pragma("unroll")                                                     \
        for (int i = 0; i < 8; ++i) {                                         \
            int f = tid + 256 * i;                                            \
            int row = f >> 5, e0 = (f & 31) << 2;                             \
            int kv = (tb_) + row;                                             \
            const float* pk = (kv < KVLEN - QL)                               \
                ? cachek + ((size_t)b * KVLEN + kv + QL) * HD + e0            \
                : kws + ((size_t)b * QL + (kv - (KVLEN - QL))) * HD + e0;     \
            kpre[i] = *(const float4*)pk;                                     \
        }                                                                     \
    } while (0)

#define PREFETCH_V(tb_)                                                       \
    do {                                                                      \
        _Pragma("unroll")                                                     \
        for (int i = 0; i < 8; ++i) {                                         \
            int kv0 = (tb_) + (vkq + 2 * i) * 4;                              \
            _Pragma("unroll")                                                 \
            for (int j = 0; j < 4; ++j) {                                     \
                int kv = kv0 + j;                                             \
                const float* pv = (kv < KVLEN - QL)                           \
                    ? cachev + ((size_t)b * KVLEN + kv + QL) * HD + ve        \
                    : vws + ((size_t)b * QL + (kv - (KVLEN - QL))) * HD + ve; \
                vpre[i][j] = *pv;                                             \
            }                                                                 \
        }                                                                     \
    } while (0)

#define PREFETCH_B(toff_)                                                     \
    do {                                                                      \
        _Pragma("unroll")                                                     \
        for (int nt = 0; nt < 4; ++nt)                                        \
            _Pragma("unroll")                                                 \
            for (int reg = 0; reg < 4; ++reg)                                 \
                bpre[nt * 4 + reg] = bptr[reg][(toff_) + nt * 16];            \
    } while (0)

#define STORE_K(ks_)                                                          \
    do {                                                                      \
        _Pragma("unroll")                                                     \
        for (int i = 0; i < 8; ++i) {                                         \
            int f = tid + 256 * i;                                            \
            int row = f >> 5, e0 = (f & 31) << 2;                             \
            *(uint2*)&ks_[row][e0] =                                          \
                make_uint2(pack2(kpre[i].x, kpre[i].y),                       \
                           pack2(kpre[i].z, kpre[i].w));                      \
        }                                                                     \
    } while (0)

#define STORE_V(vs_)                                                          \
    do {                                                                      \
        _Pragma("unroll")                                                     \
        for (int i = 0; i < 8; ++i) {                                         \
            int kv0 = (vkq + 2 * i) * 4;                                      \
            *(uint2*)&vs_[ve][kv0] =                                          \
                make_uint2(pack2(vpre[i][0], vpre[i][1]),                     \
                           pack2(vpre[i][2], vpre[i][3]));                    \
        }                                                                     \
    } while (0)

#define COMPUTE_TILE(bias_, ks_, vs_)                                         \
    do {                                                                      \
        f32x4 sacc[4];                                                        \
        _Pragma("unroll")                                                     \
        for (int nt = 0; nt < 4; ++nt) sacc[nt] = (f32x4){0.f, 0.f, 0.f, 0.f};\
        __builtin_amdgcn_s_setprio(1);                                        \
        _Pragma("unroll")                                                     \
        for (int kf = 0; kf < 4; ++kf) {                                      \
            _Pragma("unroll")                                                 \
            for (int nt = 0; nt < 4; ++nt) {                                  \
                bf16x8 kfb = *(const bf16x8*)&ks_[nt * 16 + l15][kf * 32 + quad * 8]; \
                sacc[nt] = __builtin_amdgcn_mfma_f32_16x16x32_bf16(qf[kf], kfb, sacc[nt], 0, 0, 0); \
            }                                                                 \
        }                                                                     \
        __builtin_amdgcn_s_setprio(0);                                        \
        _Pragma("unroll")                                                     \
        for (int nt = 0; nt < 4; ++nt)                                        \
            _Pragma("unroll")                                                 \
            for (int reg = 0; reg < 4; ++reg) {                               \
                float s = sacc[nt][reg] * scale + bias_[nt * 4 + reg];        \
                float p = __expf(s);                                          \
                unsigned short pb = cvt_bf16(p);                              \
                lrow[reg] += bf16_to_f32(pb);                                 \
                p_s[wave][quad * 4 + reg][nt * 16 + l15] = pb;                \
            }                                                                 \
        __builtin_amdgcn_s_setprio(1);                                        \
        _Pragma("unroll")                                                     \
        for (int kfp = 0; kfp < 2; ++kfp) {                                   \
            uint2 plo = *(const uint2*)&p_s[wave][l15][kfp * 32 + quad * 8];  \
            uint2 phi = *(const uint2*)&p_s[wave][l15][kfp * 32 + quad * 8 + 4]; \
            bf16x8 pf = mk_frag(plo.x, plo.y, phi.x, phi.y);                  \
            _Pragma("unroll")                                                 \
            for (int n8 = 0; n8 < 8; ++n8) {                                  \
                uint2 vlo = *(const uint2*)&vs_[n8 * 16 + l15][kfp * 32 + quad * 8]; \
                uint2 vhi = *(const uint2*)&vs_[n8 * 16 + l15][kfp * 32 + quad * 8 + 4]; \
                bf16x8 vf = mk_frag(vlo.x, vlo.y, vhi.x, vhi.y);              \
                oa[n8] = __builtin_amdgcn_mfma_f32_16x16x32_bf16(pf, vf, oa[n8], 0, 0, 0); \
            }                                                                 \
        }                                                                     \
        __builtin_amdgcn_s_setprio(0);                                        \
    } while (0)

__global__ __launch_bounds__(256, 2) void attn_kernel(
    const float* __restrict__ qws, const float* __restrict__ kws,
    const float* __restrict__ vws,
    const float* __restrict__ cachek, const float* __restrict__ cachev,
    const float* __restrict__ abias,
    float* __restrict__ oacc, float* __restrict__ lacc)
{
    const int ck = blockIdx.x;
    const int b  = blockIdx.y;
    const int tid = threadIdx.x;
    const int wave = tid >> 6, lane = tid & 63;
    const int l15 = lane & 15, quad = lane >> 4;
    const float scale = 0.08838834764831845f;   // 1/sqrt(128)

    // double-buffered K/V tiles
    __shared__ alignas(16) unsigned short k_s0[KT][136];   // [kv][e], 272B rows
    __shared__ alignas(16) unsigned short k_s1[KT][136];
    __shared__ alignas(16) unsigned short v_s0[HD][68];    // [e][kv], 136B rows
    __shared__ alignas(16) unsigned short v_s1[HD][68];
    __shared__ alignas(16) unsigned short p_s[4][16][72];  // wave-private [m][kv]

    // ---- Q A-frags: m=l15 (row hq=16w+l15), k=e ----
    bf16x8 qf[4];
    {
        const float* qrow = qws + ((size_t)b * HQ + 16 * wave + l15) * HD;
        #pragma unroll
        for (int kf = 0; kf < 4; ++kf) {
            float4 f0 = *(const float4*)&qrow[kf * 32 + quad * 8];
            float4 f1 = *(const float4*)&qrow[kf * 32 + quad * 8 + 4];
            qf[kf] = mk_frag(pack2(f0.x, f0.y), pack2(f0.z, f0.w),
                             pack2(f1.x, f1.y), pack2(f1.z, f1.w));
        }
    }

    const int kbase0 = ck * CHUNK;
    // K staging coords: f = tid+256i -> row=f>>5, e0=(f&31)*4
    // V staging coords: e = tid&127, kv quad base = 4*((tid>>7)+2i)
    const int ve = tid & 127;
    const int vkq = (tid >> 7);

    // bias pointers (rows quad*4+reg of this wave's m-tile)
    const float* bptr[4];
    #pragma unroll
    for (int reg = 0; reg < 4; ++reg) {
        int hq = 16 * wave + quad * 4 + reg;
        int h = hq >> 2, q = hq & 3;
        bptr[reg] = abias + (((size_t)(b * NH + h)) * QL + q) * KVLEN + kbase0 + l15;
    }

    float4 kpre[8];
    float vpre[8][4];
    float bpre[16];                      // 1-deep bias prefetch

    // ---- prologue: t0 -> buf0; then issue t1 loads (fly over tile 0) ----
    PREFETCH_K(kbase0);
    PREFETCH_V(kbase0);
    STORE_K(k_s0);
    STORE_V(v_s0);
    PREFETCH_K(kbase0 + KT);
    PREFETCH_V(kbase0 + KT);
    PREFETCH_B(0);

    f32x4 oa[8];
    #pragma unroll
    for (int n8 = 0; n8 < 8; ++n8) oa[n8] = (f32x4){0.f, 0.f, 0.f, 0.f};
    float lrow[4] = {0.f, 0.f, 0.f, 0.f};

    for (int tt = 0; tt < NT; tt += 2) {
        // ---- even tile tt: compute buf0, stage t+1 into buf1 ----
        {
            __syncthreads();            // buf0 stores visible; buf1 reads done
            float bias[16];
            #pragma unroll
            for (int j = 0; j < 16; ++j) bias[j] = bpre[j];
            PREFETCH_B((tt + 1) * KT);  // bias t+1 (tt+1 <= 7 always)
            COMPUTE_TILE(bias, k_s0, v_s0);
            STORE_K(k_s1);              // drains K(t+1); V(t+1) stays in flight
            if (tt + 2 < NT) PREFETCH_K(kbase0 + (tt + 2) * KT);
            STORE_V(v_s1);              // drains V(t+1); K(t+2) in flight
            if (tt + 2 < NT) PREFETCH_V(kbase0 + (tt + 2) * KT);
        }
        // ---- odd tile tt+1: compute buf1, stage t+2 into buf0 ----
        {
            __syncthreads();
            float bias[16];
            #pragma unroll
            for (int j = 0; j < 16; ++j) bias[j] = bpre[j];
            if (tt + 2 < NT) PREFETCH_B((tt + 2) * KT);
            COMPUTE_TILE(bias, k_s1, v_s1);
            if (tt + 2 < NT) {
                STORE_K(k_s0);
                if (tt + 3 < NT) PREFETCH_K(kbase0 + (tt + 3) * KT);
                STORE_V(v_s0);
                if (tt + 3 < NT) PREFETCH_V(kbase0 + (tt + 3) * KT);
            }
        }
    }
    // ---- reduce row sums over the 16 col-lanes ----
    #pragma unroll
    for (int reg = 0; reg < 4; ++reg) {
        float v = lrow[reg];
        v += __shfl_xor(v, 1);
        v += __shfl_xor(v, 2);
        v += __shfl_xor(v, 4);
        v += __shfl_xor(v, 8);
        lrow[reg] = v;
    }
    // ---- atomic-accumulate partial O + l across the 16 chunks of batch b ----
    const size_t abase = (size_t)b * HQ * HD;
    #pragma unroll
    for (int n8 = 0; n8 < 8; ++n8)
        #pragma unroll
        for (int reg = 0; reg < 4; ++reg) {
            int hq = 16 * wave + quad * 4 + reg;
            int e = n8 * 16 + l15;
            atomicAdd(&oacc[abase + (size_t)hq * HD + e], oa[n8][reg]);
        }
    if (l15 == 0) {
        #pragma unroll
        for (int reg = 0; reg < 4; ++reg) {
            int hq = 16 * wave + quad * 4 + reg;
            atomicAdd(&lacc[b * HQ + hq], lrow[reg]);
        }
    }
}

// ---------------------------------------------------------------------------
extern "C" void kernel_launch(void* const* d_in, const int* in_sizes, int n_in,
                              void* d_out, int out_size, void* d_ws, size_t ws_size,
                              hipStream_t stream)
{
    const float* x   = (const float*)d_in[0];
    const float* ab  = (const float*)d_in[1];
    const float* cK  = (const float*)d_in[2];
    const float* cV  = (const float*)d_in[3];
    const float* wq  = (const float*)d_in[4];
    const float* bq  = (const float*)d_in[5];
    const float* wk  = (const float*)d_in[6];
    const float* bk  = (const float*)d_in[7];
    const float* wv  = (const float*)d_in[8];
    const float* bv  = (const float*)d_in[9];
    const float* wo  = (const float*)d_in[10];
    const float* bo  = (const float*)d_in[11];
    float* out = (float*)d_out;

    // workspace (floats), contiguous
    float* ws   = (float*)d_ws;
    float* wsq  = ws;                    // 32*64*128  = 262144
    float* wsk  = wsq + 262144;          // 16384
    float* wsv  = wsk + 16384;           // 16384
    float* oacc = wsv + 16384;           // 32*64*128 = 262144 (atomic accum)
    float* lacc = oacc + 262144;         // 2048 (atomic accum)

    // one memset over all atomic targets except `out` (zeroed inside gemm0)
    hipMemsetAsync(ws, 0,
        (size_t)(262144 + 16384 + 16384 + 262144 + 2048) * sizeof(float),
        stream);

    gemm_kernel<0><<<dim3(36, 2, 4), 256, 0, stream>>>(
        x, wq, wk, wv, bq, bk, bv, wsq, wsk, wsv, out);
    attn_kernel<<<dim3(NCK, BATCH), 256, 0, stream>>>(
        wsq, wsk, wsv, cK, cV, ab, oacc, lacc);
    gemm_kernel<1><<<dim3(32, 2, 4), 256, 0, stream>>>(
        oacc, wo, lacc, nullptr, bo, nullptr, nullptr, out, nullptr, nullptr,
        nullptr);
}